// Round 12
// baseline (233.707 us; speedup 1.0000x reference)
//
#include <hip/hip_runtime.h>

typedef unsigned short u16;
typedef unsigned int u32;
typedef __bf16 bf16x8 __attribute__((ext_vector_type(8)));
typedef float floatx4 __attribute__((ext_vector_type(4)));
typedef unsigned short u16x8 __attribute__((ext_vector_type(8)));
typedef unsigned int u32x4 __attribute__((ext_vector_type(4)));

static constexpr int B_ = 4;
static constexpr int N_ = 16384;
static constexpr int M_ = 512;

__device__ __forceinline__ u16 f2bf(float f) {
    u32 u = __float_as_uint(f);
    u32 r = (u + 0x7fffu + ((u >> 16) & 1u)) >> 16;
    return (u16)r;
}
__device__ __forceinline__ float bf2f(u16 x) {
    return __uint_as_float(((u32)x) << 16);
}
__device__ __forceinline__ u32 pack2(float a, float b) {
    return (u32)f2bf(a) | ((u32)f2bf(b) << 16);
}

struct WConvArgs { const float* src[12]; };

// Weight arena layout (elements), K padded so all KS are even; knnb1 K=192.
// conv1 off 0 KP32 | conv2 2048 KP64 | conv3 6144 KP64 | conv4 10240 KP128
// conv5 26624 KP128 | knnb1 43008 KP192 | knnb2 92160 KP256 | knnb3 157696 KP256
// knna1 223232 KP512 | knna2 485376 KP512 | mlp1 747520 KP640 | mlp2 1075200 KP512
// total 1206272 elements (+2048 pad for unconditional prefetch overrun)

// ---------------------------------------------------------------------------
// prep_kernel: blocks [0,2048) ball query; [2048,2560) knn (4 nodes/block);
// [2560,7272) weight fp32->bf16 conversion. All parts independent.
// ---------------------------------------------------------------------------
__global__ __launch_bounds__(256) void prep_kernel(
    const float* __restrict__ x, const float* __restrict__ node,
    int* __restrict__ idx, int* __restrict__ knn,
    WConvArgs wa, u16* __restrict__ Wbf) {
    int bid = blockIdx.x;
    int tid = threadIdx.x, wave = tid >> 6, lane = tid & 63;

    if (bid < 2048) {
        // ---- ball query: 4 waves per (b,m); 4-iter batched loads ----
        int bm = bid;
        int b = bm >> 9, m = bm & 511;
        __shared__ int sidx[4][64];
        __shared__ int scnt[4];
        const float* xb = x + (size_t)b * 3 * N_;
        float nx = node[((size_t)b * 3 + 0) * M_ + m];
        float ny = node[((size_t)b * 3 + 1) * M_ + m];
        float nz = node[((size_t)b * 3 + 2) * M_ + m];
        float aa = nx * nx + ny * ny + nz * nz;
        int cnt = 0;
        int base = wave * 4096;
        for (int n0 = base; n0 < base + 4096; n0 += 256) {
            float px[4], py[4], pz[4];
#pragma unroll
            for (int i = 0; i < 4; ++i) {
                int n = n0 + i * 64 + lane;
                px[i] = xb[n]; py[i] = xb[N_ + n]; pz[i] = xb[2 * N_ + n];
            }
#pragma unroll
            for (int i = 0; i < 4; ++i) {
                float bb = px[i] * px[i] + py[i] * py[i] + pz[i] * pz[i];
                float d = aa + bb - 2.0f * (nx * px[i] + ny * py[i] + nz * pz[i]);
                bool inb = d < 4.0f;
                unsigned long long mask = __ballot(inb);
                if (inb && cnt < 64) {
                    int pos = cnt + __popcll(mask & ((1ull << lane) - 1ull));
                    if (pos < 64) sidx[wave][pos] = n0 + i * 64 + lane;
                }
                cnt += __popcll(mask);
            }
            if (cnt >= 64) break;   // wave-uniform; truncated counts stay >=64
        }
        if (lane == 0) scnt[wave] = cnt;
        __syncthreads();
        if (tid < 64) {
            int total = scnt[0] + scnt[1] + scnt[2] + scnt[3];
            int v = 0;
            if (total > 0) {
                int lim = total < 64 ? total : 64;
                int slot = tid < lim ? tid : 0;
                int w = 0, pre = 0;
                while (w < 3 && slot >= pre + scnt[w]) { pre += scnt[w]; ++w; }
                v = sidx[w][slot - pre];
            }
            idx[(size_t)bm * 64 + tid] = v;
        }
    } else if (bid < 2560) {
        // ---- knn: wave handles node (bid-2048)*4 + wave ----
        int bm = (bid - 2048) * 4 + wave;
        int b = bm >> 9, m = bm & 511;
        const float* nb = node + (size_t)b * 3 * M_;
        float nx = nb[m], ny = nb[M_ + m], nz = nb[2 * M_ + m];
        float aa = nx * nx + ny * ny + nz * nz;
        float dist[8];
        int didx[8];
#pragma unroll
        for (int i = 0; i < 8; ++i) {
            int n = lane + i * 64;
            float px = nb[n], py = nb[M_ + n], pz = nb[2 * M_ + n];
            float bb = px * px + py * py + pz * pz;
            float ab = nx * px + ny * py + nz * pz;
            dist[i] = aa + bb - 2.0f * ab;
            didx[i] = n;
        }
        for (int r = 0; r < 9; ++r) {
            float bv = dist[0]; int bi = didx[0]; int bslot = 0;
#pragma unroll
            for (int i = 1; i < 8; ++i) {
                if (dist[i] < bv || (dist[i] == bv && didx[i] < bi)) {
                    bv = dist[i]; bi = didx[i]; bslot = i;
                }
            }
            float rv = bv; int ri = bi;
            for (int off = 32; off > 0; off >>= 1) {
                float ov = __shfl_down(rv, off);
                int   oi = __shfl_down(ri, off);
                if (ov < rv || (ov == rv && oi < ri)) { rv = ov; ri = oi; }
            }
            ri = __shfl(ri, 0);
            if (lane == 0) knn[(size_t)bm * 9 + r] = ri;
            if (bi == ri) dist[bslot] = 3.0e38f;
        }
    } else {
        // ---- weight conversion ----
        const int CI[12] = {6, 64, 64, 128, 128, 131, 256, 256, 512, 512, 640, 512};
        const int KP[12] = {32, 64, 64, 128, 128, 192, 256, 256, 512, 512, 640, 512};
        const int OFF[13] = {0, 2048, 6144, 10240, 26624, 43008, 92160, 157696,
                             223232, 485376, 747520, 1075200, 1206272};
        int e = (bid - 2560) * 256 + tid;
        int w = 0;
        while (e >= OFF[w + 1]) ++w;
        int local = e - OFF[w];
        int kp = KP[w];
        int co = local / kp, k = local - co * kp;
        float v = 0.0f;
        if (w == 5) {   // knnb1 K-layout: 0..2 coords, 8..135 feat1, rest 0
            if (k < 3) v = wa.src[5][(size_t)co * 131 + k];
            else if (k >= 8 && k < 136) v = wa.src[5][(size_t)co * 131 + (k - 5)];
        } else if (k < CI[w]) {
            v = wa.src[w][(size_t)co * CI[w] + k];
        }
        Wbf[e] = f2bf(v);
    }
}

// ---------------------------------------------------------------------------
// Fused stage 1: one block per 2 nodes (128 rows), 256 threads (unchanged).
// ---------------------------------------------------------------------------
static constexpr int RS = 136;

__device__ __forceinline__ bf16x8 ldsA(const u16* act, int rf, int l15, int quad, int ks) {
    return *(const bf16x8*)(act + (rf * 16 + l15) * RS + ks * 32 + quad * 8);
}
__device__ __forceinline__ bf16x8 ldW(const u16* W, int ks, int l15, int quad, int kstride) {
    return *(const bf16x8*)(W + (size_t)l15 * kstride + ks * 32 + quad * 8);
}

__global__ __launch_bounds__(256, 3) void fused_stage1_kernel(
    const float* __restrict__ x, const float* __restrict__ sn,
    const float* __restrict__ node, const int* __restrict__ idx,
    const u16* __restrict__ Wbf,
    const float* __restrict__ b1, const float* __restrict__ b2,
    const float* __restrict__ b3, const float* __restrict__ b4,
    const float* __restrict__ b5, u16* __restrict__ h) {
    __shared__ __align__(16) u16 act[128 * RS];   // 34,816 B
    __shared__ __align__(16) u16 mv[2][64];
    int blk = blockIdx.x;              // 0..1023
    int bm0 = blk * 2;
    int tid = threadIdx.x, wave = tid >> 6, lane = tid & 63;
    int quad = lane >> 4, l15 = lane & 15;

    {   // gather 2 nodes x 64 neighbors
        int row = tid & 127, grp = tid >> 7;
        int bm = bm0 + (row >> 6);
        int b = bm >> 9, m = bm & 511;
        int j = idx[(size_t)bm * 64 + (row & 63)];
        const float* xb = x + (size_t)b * 3 * N_;
        const float* sb = sn + (size_t)b * 3 * N_;
        u16* r = act + row * RS;
        if (grp == 0) {
            float c0 = xb[j]          - node[((size_t)b * 3 + 0) * M_ + m];
            float c1 = xb[N_ + j]     - node[((size_t)b * 3 + 1) * M_ + m];
            float c2 = xb[2 * N_ + j] - node[((size_t)b * 3 + 2) * M_ + m];
            *(u32*)(r)     = pack2(c0, c1);
            *(u32*)(r + 2) = pack2(c2, sb[j]);
        } else {
            *(u32*)(r + 4) = pack2(sb[N_ + j], sb[2 * N_ + j]);
            *(u32*)(r + 6) = 0u;
            u32x4* z = (u32x4*)(r + 8);
            z[0] = (u32x4){0u, 0u, 0u, 0u};
            z[1] = (u32x4){0u, 0u, 0u, 0u};
            z[2] = (u32x4){0u, 0u, 0u, 0u};
        }
    }
    __syncthreads();

    {   // conv1: K=32 (6 used), co 64 (wave owns 16)
        const u16* Wp = Wbf + (size_t)(wave * 16) * 32;
        bf16x8 bw = ldW(Wp, 0, l15, quad, 32);
        floatx4 c[8];
#pragma unroll
        for (int rf = 0; rf < 8; ++rf) {
            bf16x8 a = ldsA(act, rf, l15, quad, 0);
            c[rf] = __builtin_amdgcn_mfma_f32_16x16x32_bf16(a, bw, (floatx4){0.f,0.f,0.f,0.f}, 0, 0, 0);
        }
        float bias = b1[wave * 16 + l15];
        __syncthreads();
#pragma unroll
        for (int rf = 0; rf < 8; ++rf)
#pragma unroll
            for (int r = 0; r < 4; ++r)
                act[(rf * 16 + quad * 4 + r) * RS + wave * 16 + l15] = f2bf(fmaxf(c[rf][r] + bias, 0.0f));
        __syncthreads();
    }

    const int WOFF23[2] = {2048, 6144};
    const float* bp23[2] = {b2, b3};
#pragma unroll 1
    for (int cv = 0; cv < 2; ++cv) {   // conv2 / conv3: K=64, co 64
        const u16* Wp = Wbf + WOFF23[cv] + (size_t)(wave * 16) * 64;
        bf16x8 bw0 = ldW(Wp, 0, l15, quad, 64);
        bf16x8 bw1 = ldW(Wp, 1, l15, quad, 64);
        floatx4 c[8] = {};
#pragma unroll
        for (int ks = 0; ks < 2; ++ks)
#pragma unroll
            for (int rf = 0; rf < 8; ++rf) {
                bf16x8 a = ldsA(act, rf, l15, quad, ks);
                c[rf] = __builtin_amdgcn_mfma_f32_16x16x32_bf16(a, ks ? bw1 : bw0, c[rf], 0, 0, 0);
            }
        float bias = bp23[cv][wave * 16 + l15];
        float mxA = 0.0f, mxB = 0.0f;
#pragma unroll
        for (int rf = 0; rf < 8; ++rf)
#pragma unroll
            for (int r = 0; r < 4; ++r) {
                float v = fmaxf(c[rf][r] + bias, 0.0f);
                if (rf < 4) mxA = fmaxf(mxA, v); else mxB = fmaxf(mxB, v);
            }
        __syncthreads();
#pragma unroll
        for (int rf = 0; rf < 8; ++rf)
#pragma unroll
            for (int r = 0; r < 4; ++r)
                act[(rf * 16 + quad * 4 + r) * RS + wave * 16 + l15] = f2bf(fmaxf(c[rf][r] + bias, 0.0f));
        if (cv == 1) {
            mxA = fmaxf(mxA, __shfl_xor(mxA, 16));
            mxA = fmaxf(mxA, __shfl_xor(mxA, 32));
            mxB = fmaxf(mxB, __shfl_xor(mxB, 16));
            mxB = fmaxf(mxB, __shfl_xor(mxB, 32));
            if (quad == 0) {
                mv[0][wave * 16 + l15] = f2bf(mxA);
                mv[1][wave * 16 + l15] = f2bf(mxB);
            }
        }
        __syncthreads();
    }

    {   // conv4: K=128 ([conv3 | per-node rowmax]), co 128 (wave owns 32)
        const u16* Wp = Wbf + 10240 + (size_t)(wave * 32) * 128;
        bf16x8 bw[2][4];
#pragma unroll
        for (int cf = 0; cf < 2; ++cf)
#pragma unroll
            for (int ks = 0; ks < 4; ++ks)
                bw[cf][ks] = ldW(Wp + (size_t)cf * 16 * 128, ks, l15, quad, 128);
        floatx4 c[8][2] = {};
#pragma unroll
        for (int ks = 0; ks < 4; ++ks)
#pragma unroll
            for (int rf = 0; rf < 8; ++rf) {
                bf16x8 a = (ks < 2) ? ldsA(act, rf, l15, quad, ks)
                                    : *(const bf16x8*)(&mv[rf >> 2][(ks - 2) * 32 + quad * 8]);
#pragma unroll
                for (int cf = 0; cf < 2; ++cf)
                    c[rf][cf] = __builtin_amdgcn_mfma_f32_16x16x32_bf16(a, bw[cf][ks], c[rf][cf], 0, 0, 0);
            }
        float bias[2];
#pragma unroll
        for (int cf = 0; cf < 2; ++cf) bias[cf] = b4[wave * 32 + cf * 16 + l15];
        __syncthreads();
#pragma unroll
        for (int rf = 0; rf < 8; ++rf)
#pragma unroll
            for (int cf = 0; cf < 2; ++cf)
#pragma unroll
                for (int r = 0; r < 4; ++r)
                    act[(rf * 16 + quad * 4 + r) * RS + wave * 32 + cf * 16 + l15] =
                        f2bf(fmaxf(c[rf][cf][r] + bias[cf], 0.0f));
        __syncthreads();
    }

    {   // conv5 + per-node maxpool -> h[bm][0:128]
        const u16* Wp = Wbf + 26624 + (size_t)(wave * 32) * 128;
        bf16x8 bw[2][4];
#pragma unroll
        for (int cf = 0; cf < 2; ++cf)
#pragma unroll
            for (int ks = 0; ks < 4; ++ks)
                bw[cf][ks] = ldW(Wp + (size_t)cf * 16 * 128, ks, l15, quad, 128);
        floatx4 c[8][2] = {};
#pragma unroll
        for (int ks = 0; ks < 4; ++ks)
#pragma unroll
            for (int rf = 0; rf < 8; ++rf) {
                bf16x8 a = ldsA(act, rf, l15, quad, ks);
#pragma unroll
                for (int cf = 0; cf < 2; ++cf)
                    c[rf][cf] = __builtin_amdgcn_mfma_f32_16x16x32_bf16(a, bw[cf][ks], c[rf][cf], 0, 0, 0);
            }
#pragma unroll
        for (int cf = 0; cf < 2; ++cf) {
            float bias = b5[wave * 32 + cf * 16 + l15];
            float mxA = 0.0f, mxB = 0.0f;
#pragma unroll
            for (int rf = 0; rf < 8; ++rf)
#pragma unroll
                for (int r = 0; r < 4; ++r) {
                    float v = fmaxf(c[rf][cf][r] + bias, 0.0f);
                    if (rf < 4) mxA = fmaxf(mxA, v); else mxB = fmaxf(mxB, v);
                }
            mxA = fmaxf(mxA, __shfl_xor(mxA, 16));
            mxA = fmaxf(mxA, __shfl_xor(mxA, 32));
            mxB = fmaxf(mxB, __shfl_xor(mxB, 16));
            mxB = fmaxf(mxB, __shfl_xor(mxB, 32));
            if (quad == 0) {
                h[(size_t)bm0 * 640 + wave * 32 + cf * 16 + l15] = f2bf(mxA);
                h[(size_t)(bm0 + 1) * 640 + wave * 32 + cf * 16 + l15] = f2bf(mxB);
            }
        }
    }
}

// ---------------------------------------------------------------------------
// ROLLED in-LDS in-place conv (small code footprint). KS must be even; 2
// k-steps per iteration with static A/B register ping-pong; next-iteration
// weights prefetched unconditionally (reads stay inside Wbf + 4KB pad).
// ---------------------------------------------------------------------------
template <int CF, int RF, int RSx>
__device__ __forceinline__ void conv_loop(u16* act, const u16* __restrict__ W0,
                                          int KP, int KS,
                                          const float* __restrict__ bias, int cb,
                                          int l15, int quad) {
    floatx4 acc[RF][CF];
#pragma unroll
    for (int rf = 0; rf < RF; ++rf)
#pragma unroll
        for (int cf = 0; cf < CF; ++cf) acc[rf][cf] = (floatx4){0.f, 0.f, 0.f, 0.f};

    const u16* wl = W0 + (size_t)(cb + l15) * KP + quad * 8;
    const u16* al = act + (size_t)l15 * RSx + quad * 8;
    bf16x8 bwA[CF], bwB[CF];
#pragma unroll
    for (int cf = 0; cf < CF; ++cf) {
        bwA[cf] = *(const bf16x8*)(wl + (size_t)cf * 16 * KP);
        bwB[cf] = *(const bf16x8*)(wl + (size_t)cf * 16 * KP + 32);
    }
#pragma unroll 1
    for (int ks = 0; ks < KS; ks += 2) {
        bf16x8 a0[RF], a1[RF], nA[CF], nB[CF];
#pragma unroll
        for (int rf = 0; rf < RF; ++rf) {
            a0[rf] = *(const bf16x8*)(al + rf * 16 * RSx + ks * 32);
            a1[rf] = *(const bf16x8*)(al + rf * 16 * RSx + ks * 32 + 32);
        }
#pragma unroll
        for (int cf = 0; cf < CF; ++cf) {
            nA[cf] = *(const bf16x8*)(wl + (size_t)cf * 16 * KP + (ks + 2) * 32);
            nB[cf] = *(const bf16x8*)(wl + (size_t)cf * 16 * KP + (ks + 3) * 32);
        }
#pragma unroll
        for (int rf = 0; rf < RF; ++rf)
#pragma unroll
            for (int cf = 0; cf < CF; ++cf)
                acc[rf][cf] = __builtin_amdgcn_mfma_f32_16x16x32_bf16(a0[rf], bwA[cf], acc[rf][cf], 0, 0, 0);
#pragma unroll
        for (int rf = 0; rf < RF; ++rf)
#pragma unroll
            for (int cf = 0; cf < CF; ++cf)
                acc[rf][cf] = __builtin_amdgcn_mfma_f32_16x16x32_bf16(a1[rf], bwB[cf], acc[rf][cf], 0, 0, 0);
#pragma unroll
        for (int cf = 0; cf < CF; ++cf) { bwA[cf] = nA[cf]; bwB[cf] = nB[cf]; }
    }
    __syncthreads();   // all waves' reads complete before in-place writes
#pragma unroll
    for (int cf = 0; cf < CF; ++cf) {
        float bs = bias[cb + cf * 16 + l15];
#pragma unroll
        for (int rf = 0; rf < RF; ++rf)
#pragma unroll
            for (int r = 0; r < 4; ++r)
                act[(rf * 16 + quad * 4 + r) * RSx + cb + cf * 16 + l15] =
                    f2bf(fmaxf(acc[rf][cf][r] + bs, 0.0f));
    }
    __syncthreads();
}

// ---------------------------------------------------------------------------
// Fused stage 2: one block per 8 nodes, 512 threads (8 waves).
// knnb1 K padded to 192 (act cols 160..191 zeroed, weights padded to match).
// ---------------------------------------------------------------------------
static constexpr int RS2 = 520;

__global__ __launch_bounds__(512, 2) void fused_stage2_kernel(
    const float* __restrict__ node, u16* __restrict__ h, const int* __restrict__ knn,
    const u16* __restrict__ Wbf,
    const float* __restrict__ bb1, const float* __restrict__ bb2,
    const float* __restrict__ bb3, const float* __restrict__ ba1,
    const float* __restrict__ ba2) {
    __shared__ __align__(16) u16 act[80 * RS2];   // 83,200 B
    int blk = blockIdx.x;              // 0..255
    int node0 = blk * 8;
    int b = node0 >> 9;
    int tid = threadIdx.x, wave = tid >> 6, lane = tid & 63;
    int quad = lane >> 4, l15 = lane & 15;
    (void)lane;

    for (int e = tid; e < 80 * 24; e += 512)   // zero cols 0..191
        *(u16x8*)(act + (e / 24) * RS2 + (e % 24) * 8) = (u16x8){0,0,0,0,0,0,0,0};
    __syncthreads();
    for (int e = tid; e < 72 * 3; e += 512) {
        int r = e / 3, c = e - r * 3;
        int nodei = node0 + r / 9;
        int j = knn[(size_t)nodei * 9 + (r % 9)];
        float v = node[((size_t)b * 3 + c) * M_ + j] - node[((size_t)b * 3 + c) * M_ + (nodei & 511)];
        act[r * RS2 + c] = f2bf(v);
    }
    for (int e = tid; e < 72 * 16; e += 512) {
        int r = e >> 4, s = e & 15;
        int nodei = node0 + r / 9;
        int j = knn[(size_t)nodei * 9 + (r % 9)];
        *(u16x8*)(act + r * RS2 + 8 + s * 8) =
            *(const u16x8*)(h + (size_t)(b * 512 + j) * 640 + s * 8);
    }
    __syncthreads();

    conv_loop<2, 5, RS2>(act, Wbf + 43008, 192, 6, bb1, wave * 32, l15, quad);
    conv_loop<2, 5, RS2>(act, Wbf + 92160, 256, 8, bb2, wave * 32, l15, quad);
    conv_loop<2, 5, RS2>(act, Wbf + 157696, 256, 8, bb3, wave * 32, l15, quad);

    for (int e = tid; e < 8 * 32; e += 512) {
        int li = e >> 5, s = e & 31;
        int r0 = li * 9;
        float mx[8];
#pragma unroll
        for (int i = 0; i < 8; ++i) mx[i] = -3.0e38f;
#pragma unroll
        for (int kk = 0; kk < 9; ++kk) {
            u16x8 v = *(const u16x8*)(act + (r0 + kk) * RS2 + s * 8);
#pragma unroll
            for (int i = 0; i < 8; ++i) mx[i] = fmaxf(mx[i], bf2f(v[i]));
        }
        u16x8 o;
#pragma unroll
        for (int i = 0; i < 8; ++i) o[i] = f2bf(mx[i]);
#pragma unroll
        for (int kk = 0; kk < 9; ++kk)
            *(u16x8*)(act + (r0 + kk) * RS2 + 256 + s * 8) = o;
    }
    __syncthreads();

    conv_loop<4, 5, RS2>(act, Wbf + 223232, 512, 16, ba1, wave * 64, l15, quad);
    conv_loop<4, 5, RS2>(act, Wbf + 485376, 512, 16, ba2, wave * 64, l15, quad);

    for (int e = tid; e < 8 * 64; e += 512) {
        int li = e >> 6, s = e & 63;
        int r0 = li * 9;
        float mx[8];
#pragma unroll
        for (int i = 0; i < 8; ++i) mx[i] = -3.0e38f;
#pragma unroll
        for (int kk = 0; kk < 9; ++kk) {
            u16x8 v = *(const u16x8*)(act + (r0 + kk) * RS2 + s * 8);
#pragma unroll
            for (int i = 0; i < 8; ++i) mx[i] = fmaxf(mx[i], bf2f(v[i]));
        }
        u16x8 o;
#pragma unroll
        for (int i = 0; i < 8; ++i) o[i] = f2bf(mx[i]);
        *(u16x8*)(h + (size_t)(node0 + li) * 640 + 128 + s * 8) = o;
    }
}

// ---------------------------------------------------------------------------
// Fused stage 3: 256 blocks x 8 nodes, 512 threads. Pad rows 8..15 left
// uninitialized (MFMA row r depends only on A row r; pad rows never read).
// ---------------------------------------------------------------------------
static constexpr int RS3 = 648;

__global__ __launch_bounds__(512, 2) void fused_stage3_kernel(
    const float* __restrict__ node, const u16* __restrict__ h,
    const u16* __restrict__ Wbf,
    const float* __restrict__ bm1, const float* __restrict__ bm2,
    const float* __restrict__ w3, const float* __restrict__ b3,
    float* __restrict__ out) {
    __shared__ __align__(16) u16 act[16 * RS3];   // 20,736 B
    int blk = blockIdx.x;              // 0..255
    int node0 = blk * 8;
    int tid = threadIdx.x, lane = tid & 63, wave = tid >> 6;
    int quad = lane >> 4, l15 = lane & 15;

    for (int e = tid; e < 8 * 80; e += 512) {
        int r = e / 80, seg = e - r * 80;
        *(u16x8*)(act + r * RS3 + seg * 8) =
            *(const u16x8*)(h + (size_t)(node0 + r) * 640 + seg * 8);
    }
    __syncthreads();

    conv_loop<4, 1, RS3>(act, Wbf + 747520, 640, 20, bm1, wave * 64, l15, quad);
    conv_loop<2, 1, RS3>(act, Wbf + 1075200, 512, 16, bm2, wave * 32, l15, quad);

    if (tid < 32) {
        int li = tid >> 2, oc = tid & 3;
        const u16* row = act + li * RS3;
        const float* wrow = w3 + oc * 256;
        float a = 0.0f;
        for (int c = 0; c < 256; c += 4) {
            a += bf2f(row[c]) * wrow[c];
            a += bf2f(row[c + 1]) * wrow[c + 1];
            a += bf2f(row[c + 2]) * wrow[c + 2];
            a += bf2f(row[c + 3]) * wrow[c + 3];
        }
        a += b3[oc];
        int nodei = node0 + li;
        int b = nodei >> 9, m = nodei & 511;
        if (oc < 3) {
            float nv = node[((size_t)b * 3 + oc) * M_ + m];
            out[((size_t)b * 3 + oc) * M_ + m] = nv;
            out[6144 + ((size_t)b * 3 + oc) * M_ + m] = nv + a;
        } else {
            out[12288 + nodei] = fmaxf(a, 0.0f) + log1pf(expf(-fabsf(a))) + 0.001f;
        }
    }
}

// ---------------------------------------------------------------------------
extern "C" void kernel_launch(void* const* d_in, const int* in_sizes, int n_in,
                              void* d_out, int out_size, void* d_ws, size_t ws_size,
                              hipStream_t stream) {
    (void)in_sizes; (void)n_in; (void)out_size; (void)ws_size;
    const float* x = (const float*)d_in[0];
    const float* sn = (const float*)d_in[1];
    const float* node = (const float*)d_in[2];
    const float* W[13];
    const float* Bs[13];
    for (int i = 0; i < 13; ++i) {
        W[i] = (const float*)d_in[3 + 2 * i];
        Bs[i] = (const float*)d_in[4 + 2 * i];
    }
    float* out = (float*)d_out;

    char* ws = (char*)d_ws;
    int* idx = (int*)(ws + 0);                 //   524,288
    int* knn = (int*)(ws + 524288);            //    73,728
    u16* Wbf = (u16*)(ws + 598016);            // 2,412,544 + 4,096 pad
    u16* h   = (u16*)(ws + 3014656);           // 2,621,440 (2048 x 640)

    WConvArgs wa;
    for (int w = 0; w < 12; ++w) wa.src[w] = W[w];

    prep_kernel<<<7272, 256, 0, stream>>>(x, node, idx, knn, wa, Wbf);

    fused_stage1_kernel<<<1024, 256, 0, stream>>>(x, sn, node, idx, Wbf,
                                                  Bs[0], Bs[1], Bs[2], Bs[3], Bs[4], h);
    fused_stage2_kernel<<<256, 512, 0, stream>>>(node, h, knn, Wbf,
                                                 Bs[5], Bs[6], Bs[7], Bs[8], Bs[9]);
    fused_stage3_kernel<<<256, 512, 0, stream>>>(node, h, Wbf, Bs[10], Bs[11],
                                                 W[12], Bs[12], out);
}

// Round 13
// 224.515 us; speedup vs baseline: 1.0409x; 1.0409x over previous
//
#include <hip/hip_runtime.h>

typedef unsigned short u16;
typedef unsigned int u32;
typedef __bf16 bf16x8 __attribute__((ext_vector_type(8)));
typedef float floatx4 __attribute__((ext_vector_type(4)));
typedef unsigned short u16x8 __attribute__((ext_vector_type(8)));
typedef unsigned int u32x4 __attribute__((ext_vector_type(4)));

static constexpr int B_ = 4;
static constexpr int N_ = 16384;
static constexpr int M_ = 512;

__device__ __forceinline__ u16 f2bf(float f) {
    u32 u = __float_as_uint(f);
    u32 r = (u + 0x7fffu + ((u >> 16) & 1u)) >> 16;
    return (u16)r;
}
__device__ __forceinline__ float bf2f(u16 x) {
    return __uint_as_float(((u32)x) << 16);
}
__device__ __forceinline__ u32 pack2(float a, float b) {
    return (u32)f2bf(a) | ((u32)f2bf(b) << 16);
}

struct WConvArgs { const float* src[12]; };

// ---------------------------------------------------------------------------
// prep_kernel: blocks [0,2048) ball query; [2048,2560) knn (4 nodes/block);
// [2560,7240) weight fp32->bf16 conversion. All parts independent.
// ---------------------------------------------------------------------------
__global__ __launch_bounds__(256) void prep_kernel(
    const float* __restrict__ x, const float* __restrict__ node,
    int* __restrict__ idx, int* __restrict__ knn,
    WConvArgs wa, u16* __restrict__ Wbf) {
    int bid = blockIdx.x;
    int tid = threadIdx.x, wave = tid >> 6, lane = tid & 63;

    if (bid < 2048) {
        // ---- ball query: 4 waves per (b,m); 4-iter batched loads ----
        int bm = bid;
        int b = bm >> 9, m = bm & 511;
        __shared__ int sidx[4][64];
        __shared__ int scnt[4];
        const float* xb = x + (size_t)b * 3 * N_;
        float nx = node[((size_t)b * 3 + 0) * M_ + m];
        float ny = node[((size_t)b * 3 + 1) * M_ + m];
        float nz = node[((size_t)b * 3 + 2) * M_ + m];
        float aa = nx * nx + ny * ny + nz * nz;
        int cnt = 0;
        int base = wave * 4096;
        for (int n0 = base; n0 < base + 4096; n0 += 256) {
            float px[4], py[4], pz[4];
#pragma unroll
            for (int i = 0; i < 4; ++i) {
                int n = n0 + i * 64 + lane;
                px[i] = xb[n]; py[i] = xb[N_ + n]; pz[i] = xb[2 * N_ + n];
            }
#pragma unroll
            for (int i = 0; i < 4; ++i) {
                float bb = px[i] * px[i] + py[i] * py[i] + pz[i] * pz[i];
                float d = aa + bb - 2.0f * (nx * px[i] + ny * py[i] + nz * pz[i]);
                bool inb = d < 4.0f;
                unsigned long long mask = __ballot(inb);
                if (inb && cnt < 64) {
                    int pos = cnt + __popcll(mask & ((1ull << lane) - 1ull));
                    if (pos < 64) sidx[wave][pos] = n0 + i * 64 + lane;
                }
                cnt += __popcll(mask);
            }
            if (cnt >= 64) break;   // wave-uniform; truncated counts stay >=64
        }
        if (lane == 0) scnt[wave] = cnt;
        __syncthreads();
        if (tid < 64) {
            int total = scnt[0] + scnt[1] + scnt[2] + scnt[3];
            int v = 0;
            if (total > 0) {
                int lim = total < 64 ? total : 64;
                int slot = tid < lim ? tid : 0;
                int w = 0, pre = 0;
                while (w < 3 && slot >= pre + scnt[w]) { pre += scnt[w]; ++w; }
                v = sidx[w][slot - pre];
            }
            idx[(size_t)bm * 64 + tid] = v;
        }
    } else if (bid < 2560) {
        // ---- knn: wave handles node (bid-2048)*4 + wave ----
        int bm = (bid - 2048) * 4 + wave;
        int b = bm >> 9, m = bm & 511;
        const float* nb = node + (size_t)b * 3 * M_;
        float nx = nb[m], ny = nb[M_ + m], nz = nb[2 * M_ + m];
        float aa = nx * nx + ny * ny + nz * nz;
        float dist[8];
        int didx[8];
#pragma unroll
        for (int i = 0; i < 8; ++i) {
            int n = lane + i * 64;
            float px = nb[n], py = nb[M_ + n], pz = nb[2 * M_ + n];
            float bb = px * px + py * py + pz * pz;
            float ab = nx * px + ny * py + nz * pz;
            dist[i] = aa + bb - 2.0f * ab;
            didx[i] = n;
        }
        for (int r = 0; r < 9; ++r) {
            float bv = dist[0]; int bi = didx[0]; int bslot = 0;
#pragma unroll
            for (int i = 1; i < 8; ++i) {
                if (dist[i] < bv || (dist[i] == bv && didx[i] < bi)) {
                    bv = dist[i]; bi = didx[i]; bslot = i;
                }
            }
            float rv = bv; int ri = bi;
            for (int off = 32; off > 0; off >>= 1) {
                float ov = __shfl_down(rv, off);
                int   oi = __shfl_down(ri, off);
                if (ov < rv || (ov == rv && oi < ri)) { rv = ov; ri = oi; }
            }
            ri = __shfl(ri, 0);
            if (lane == 0) knn[(size_t)bm * 9 + r] = ri;
            if (bi == ri) dist[bslot] = 3.0e38f;
        }
    } else {
        // ---- weight conversion ----
        const int CI[12] = {6, 64, 64, 128, 128, 131, 256, 256, 512, 512, 640, 512};
        const int KP[12] = {32, 64, 64, 128, 128, 160, 256, 256, 512, 512, 640, 512};
        const int OFF[13] = {0, 2048, 6144, 10240, 26624, 43008, 83968, 149504,
                             215040, 477184, 739328, 1067008, 1198080};
        int e = (bid - 2560) * 256 + tid;
        int w = 0;
        while (e >= OFF[w + 1]) ++w;
        int local = e - OFF[w];
        int kp = KP[w];
        int co = local / kp, k = local - co * kp;
        float v = 0.0f;
        if (w == 5) {   // knnb1 K-layout: 0..2 coords, 8..135 feat1
            if (k < 3) v = wa.src[5][(size_t)co * 131 + k];
            else if (k >= 8 && k < 136) v = wa.src[5][(size_t)co * 131 + (k - 5)];
        } else if (k < CI[w]) {
            v = wa.src[w][(size_t)co * CI[w] + k];
        }
        Wbf[e] = f2bf(v);
    }
}

// ---------------------------------------------------------------------------
// Fused stage 1: one block per 4 nodes (256 rows, RF=16), 256 threads,
// 2 blocks/CU. Doubles MFMA per barrier phase vs 2-node; halves weight
// re-streaming (512 blocks x 86KB = 44MB L2 traffic).
// ---------------------------------------------------------------------------
static constexpr int RS = 136;

__device__ __forceinline__ bf16x8 ldsA(const u16* act, int rf, int l15, int quad, int ks) {
    return *(const bf16x8*)(act + (rf * 16 + l15) * RS + ks * 32 + quad * 8);
}
__device__ __forceinline__ bf16x8 ldW(const u16* W, int ks, int l15, int quad, int kstride) {
    return *(const bf16x8*)(W + (size_t)l15 * kstride + ks * 32 + quad * 8);
}

__global__ __launch_bounds__(256, 2) void fused_stage1_kernel(
    const float* __restrict__ x, const float* __restrict__ sn,
    const float* __restrict__ node, const int* __restrict__ idx,
    const u16* __restrict__ Wbf,
    const float* __restrict__ b1, const float* __restrict__ b2,
    const float* __restrict__ b3, const float* __restrict__ b4,
    const float* __restrict__ b5, u16* __restrict__ h) {
    __shared__ __align__(16) u16 act[256 * RS];   // 69,632 B
    __shared__ __align__(16) u16 mv[4][64];
    int blk = blockIdx.x;              // 0..511
    int bm0 = blk * 4;
    int tid = threadIdx.x, wave = tid >> 6, lane = tid & 63;
    int quad = lane >> 4, l15 = lane & 15;

    {   // gather 4 nodes x 64 neighbors: one full row per thread
        int row = tid;
        int bm = bm0 + (row >> 6);
        int b = bm >> 9, m = bm & 511;
        int j = idx[(size_t)bm * 64 + (row & 63)];
        const float* xb = x + (size_t)b * 3 * N_;
        const float* sb = sn + (size_t)b * 3 * N_;
        float c0 = xb[j]          - node[((size_t)b * 3 + 0) * M_ + m];
        float c1 = xb[N_ + j]     - node[((size_t)b * 3 + 1) * M_ + m];
        float c2 = xb[2 * N_ + j] - node[((size_t)b * 3 + 2) * M_ + m];
        float s0 = sb[j], s1 = sb[N_ + j], s2 = sb[2 * N_ + j];
        u16* r = act + row * RS;
        *(u32*)(r)     = pack2(c0, c1);
        *(u32*)(r + 2) = pack2(c2, s0);
        *(u32*)(r + 4) = pack2(s1, s2);
        *(u32*)(r + 6) = 0u;
        u32x4* z = (u32x4*)(r + 8);
        z[0] = (u32x4){0u, 0u, 0u, 0u};
        z[1] = (u32x4){0u, 0u, 0u, 0u};
        z[2] = (u32x4){0u, 0u, 0u, 0u};
    }
    __syncthreads();

    {   // conv1: K=32 (6 used), co 64 (wave owns 16)
        const u16* Wp = Wbf + (size_t)(wave * 16) * 32;
        bf16x8 bw = ldW(Wp, 0, l15, quad, 32);
        floatx4 c[16];
#pragma unroll
        for (int rf = 0; rf < 16; ++rf) {
            bf16x8 a = ldsA(act, rf, l15, quad, 0);
            c[rf] = __builtin_amdgcn_mfma_f32_16x16x32_bf16(a, bw, (floatx4){0.f,0.f,0.f,0.f}, 0, 0, 0);
        }
        float bias = b1[wave * 16 + l15];
        __syncthreads();
#pragma unroll
        for (int rf = 0; rf < 16; ++rf)
#pragma unroll
            for (int r = 0; r < 4; ++r)
                act[(rf * 16 + quad * 4 + r) * RS + wave * 16 + l15] = f2bf(fmaxf(c[rf][r] + bias, 0.0f));
        __syncthreads();
    }

    const int WOFF23[2] = {2048, 6144};
    const float* bp23[2] = {b2, b3};
#pragma unroll 1
    for (int cv = 0; cv < 2; ++cv) {   // conv2 / conv3: K=64, co 64
        const u16* Wp = Wbf + WOFF23[cv] + (size_t)(wave * 16) * 64;
        bf16x8 bw0 = ldW(Wp, 0, l15, quad, 64);
        bf16x8 bw1 = ldW(Wp, 1, l15, quad, 64);
        floatx4 c[16] = {};
#pragma unroll
        for (int ks = 0; ks < 2; ++ks)
#pragma unroll
            for (int rf = 0; rf < 16; ++rf) {
                bf16x8 a = ldsA(act, rf, l15, quad, ks);
                c[rf] = __builtin_amdgcn_mfma_f32_16x16x32_bf16(a, ks ? bw1 : bw0, c[rf], 0, 0, 0);
            }
        float bias = bp23[cv][wave * 16 + l15];
        float mxN[4] = {0.0f, 0.0f, 0.0f, 0.0f};
#pragma unroll
        for (int rf = 0; rf < 16; ++rf)
#pragma unroll
            for (int r = 0; r < 4; ++r) {
                float v = fmaxf(c[rf][r] + bias, 0.0f);
                mxN[rf >> 2] = fmaxf(mxN[rf >> 2], v);
            }
        __syncthreads();
#pragma unroll
        for (int rf = 0; rf < 16; ++rf)
#pragma unroll
            for (int r = 0; r < 4; ++r)
                act[(rf * 16 + quad * 4 + r) * RS + wave * 16 + l15] = f2bf(fmaxf(c[rf][r] + bias, 0.0f));
        if (cv == 1) {
#pragma unroll
            for (int n = 0; n < 4; ++n) {
                float mx = mxN[n];
                mx = fmaxf(mx, __shfl_xor(mx, 16));
                mx = fmaxf(mx, __shfl_xor(mx, 32));
                if (quad == 0) mv[n][wave * 16 + l15] = f2bf(mx);
            }
        }
        __syncthreads();
    }

    {   // conv4: K=128 ([conv3 | per-node rowmax]), co 128 (wave owns 32)
        const u16* Wp = Wbf + 10240 + (size_t)(wave * 32) * 128;
        bf16x8 bw[2][4];
#pragma unroll
        for (int cf = 0; cf < 2; ++cf)
#pragma unroll
            for (int ks = 0; ks < 4; ++ks)
                bw[cf][ks] = ldW(Wp + (size_t)cf * 16 * 128, ks, l15, quad, 128);
        floatx4 c[16][2] = {};
#pragma unroll
        for (int ks = 0; ks < 4; ++ks)
#pragma unroll
            for (int rf = 0; rf < 16; ++rf) {
                bf16x8 a = (ks < 2) ? ldsA(act, rf, l15, quad, ks)
                                    : *(const bf16x8*)(&mv[rf >> 2][(ks - 2) * 32 + quad * 8]);
#pragma unroll
                for (int cf = 0; cf < 2; ++cf)
                    c[rf][cf] = __builtin_amdgcn_mfma_f32_16x16x32_bf16(a, bw[cf][ks], c[rf][cf], 0, 0, 0);
            }
        float bias[2];
#pragma unroll
        for (int cf = 0; cf < 2; ++cf) bias[cf] = b4[wave * 32 + cf * 16 + l15];
        __syncthreads();
#pragma unroll
        for (int rf = 0; rf < 16; ++rf)
#pragma unroll
            for (int cf = 0; cf < 2; ++cf)
#pragma unroll
                for (int r = 0; r < 4; ++r)
                    act[(rf * 16 + quad * 4 + r) * RS + wave * 32 + cf * 16 + l15] =
                        f2bf(fmaxf(c[rf][cf][r] + bias[cf], 0.0f));
        __syncthreads();
    }

    {   // conv5 + per-node maxpool -> h[bm][0:128]
        const u16* Wp = Wbf + 26624 + (size_t)(wave * 32) * 128;
        bf16x8 bw[2][4];
#pragma unroll
        for (int cf = 0; cf < 2; ++cf)
#pragma unroll
            for (int ks = 0; ks < 4; ++ks)
                bw[cf][ks] = ldW(Wp + (size_t)cf * 16 * 128, ks, l15, quad, 128);
        floatx4 c[16][2] = {};
#pragma unroll
        for (int ks = 0; ks < 4; ++ks)
#pragma unroll
            for (int rf = 0; rf < 16; ++rf) {
                bf16x8 a = ldsA(act, rf, l15, quad, ks);
#pragma unroll
                for (int cf = 0; cf < 2; ++cf)
                    c[rf][cf] = __builtin_amdgcn_mfma_f32_16x16x32_bf16(a, bw[cf][ks], c[rf][cf], 0, 0, 0);
            }
#pragma unroll
        for (int cf = 0; cf < 2; ++cf) {
            float bias = b5[wave * 32 + cf * 16 + l15];
            float mxN[4] = {0.0f, 0.0f, 0.0f, 0.0f};
#pragma unroll
            for (int rf = 0; rf < 16; ++rf)
#pragma unroll
                for (int r = 0; r < 4; ++r) {
                    float v = fmaxf(c[rf][cf][r] + bias, 0.0f);
                    mxN[rf >> 2] = fmaxf(mxN[rf >> 2], v);
                }
#pragma unroll
            for (int n = 0; n < 4; ++n) {
                float mx = mxN[n];
                mx = fmaxf(mx, __shfl_xor(mx, 16));
                mx = fmaxf(mx, __shfl_xor(mx, 32));
                if (quad == 0)
                    h[(size_t)(bm0 + n) * 640 + wave * 32 + cf * 16 + l15] = f2bf(mx);
            }
        }
    }
}

// ---------------------------------------------------------------------------
// In-LDS in-place conv with 4-deep weight prefetch (3 k-steps ahead in flight).
// ---------------------------------------------------------------------------
template <int KS, int CF, int RF, int RSx>
__device__ __forceinline__ void conv_inplace(u16* act, const u16* __restrict__ W0, int KP,
                                             const float* __restrict__ bias, int cb,
                                             int l15, int quad) {
    floatx4 acc[RF][CF];
#pragma unroll
    for (int rf = 0; rf < RF; ++rf)
#pragma unroll
        for (int cf = 0; cf < CF; ++cf) acc[rf][cf] = (floatx4){0.f, 0.f, 0.f, 0.f};

    bf16x8 bw[4][CF];
#pragma unroll
    for (int p = 0; p < 3; ++p)
        if (p < KS)
#pragma unroll
            for (int cf = 0; cf < CF; ++cf)
                bw[p][cf] = *(const bf16x8*)(W0 + (size_t)(cb + cf * 16 + l15) * KP +
                                             p * 32 + quad * 8);

#pragma unroll
    for (int ks = 0; ks < KS; ++ks) {
        if (ks + 3 < KS) {
#pragma unroll
            for (int cf = 0; cf < CF; ++cf)
                bw[(ks + 3) & 3][cf] = *(const bf16x8*)(W0 + (size_t)(cb + cf * 16 + l15) * KP +
                                                        (ks + 3) * 32 + quad * 8);
        }
#pragma unroll
        for (int rf = 0; rf < RF; ++rf) {
            bf16x8 a = *(const bf16x8*)(act + (rf * 16 + l15) * RSx + ks * 32 + quad * 8);
#pragma unroll
            for (int cf = 0; cf < CF; ++cf)
                acc[rf][cf] = __builtin_amdgcn_mfma_f32_16x16x32_bf16(a, bw[ks & 3][cf], acc[rf][cf], 0, 0, 0);
        }
    }
    __syncthreads();   // all waves' reads complete before in-place writes
#pragma unroll
    for (int cf = 0; cf < CF; ++cf) {
        float bs = bias[cb + cf * 16 + l15];
#pragma unroll
        for (int rf = 0; rf < RF; ++rf)
#pragma unroll
            for (int r = 0; r < 4; ++r)
                act[(rf * 16 + quad * 4 + r) * RSx + cb + cf * 16 + l15] =
                    f2bf(fmaxf(acc[rf][cf][r] + bs, 0.0f));
    }
    __syncthreads();
}

// ---------------------------------------------------------------------------
// Fused stage 2: one block per 8 nodes, 512 threads (8 waves = 2/SIMD).
// ---------------------------------------------------------------------------
static constexpr int RS2 = 520;

__global__ __launch_bounds__(512, 2) void fused_stage2_kernel(
    const float* __restrict__ node, u16* __restrict__ h, const int* __restrict__ knn,
    const u16* __restrict__ Wbf,
    const float* __restrict__ bb1, const float* __restrict__ bb2,
    const float* __restrict__ bb3, const float* __restrict__ ba1,
    const float* __restrict__ ba2) {
    __shared__ __align__(16) u16 act[80 * RS2];   // 83,200 B
    int blk = blockIdx.x;              // 0..255
    int node0 = blk * 8;
    int b = node0 >> 9;
    int tid = threadIdx.x, wave = tid >> 6, lane = tid & 63;
    int quad = lane >> 4, l15 = lane & 15;
    (void)lane;

    for (int e = tid; e < 80 * 20; e += 512)
        *(u16x8*)(act + (e / 20) * RS2 + (e % 20) * 8) = (u16x8){0,0,0,0,0,0,0,0};
    __syncthreads();
    for (int e = tid; e < 72 * 3; e += 512) {
        int r = e / 3, c = e - r * 3;
        int nodei = node0 + r / 9;
        int j = knn[(size_t)nodei * 9 + (r % 9)];
        float v = node[((size_t)b * 3 + c) * M_ + j] - node[((size_t)b * 3 + c) * M_ + (nodei & 511)];
        act[r * RS2 + c] = f2bf(v);
    }
    for (int e = tid; e < 72 * 16; e += 512) {
        int r = e >> 4, s = e & 15;
        int nodei = node0 + r / 9;
        int j = knn[(size_t)nodei * 9 + (r % 9)];
        *(u16x8*)(act + r * RS2 + 8 + s * 8) =
            *(const u16x8*)(h + (size_t)(b * 512 + j) * 640 + s * 8);
    }
    __syncthreads();

    conv_inplace<5, 2, 5, RS2>(act, Wbf + 43008, 160, bb1, wave * 32, l15, quad);
    conv_inplace<8, 2, 5, RS2>(act, Wbf + 83968, 256, bb2, wave * 32, l15, quad);
    conv_inplace<8, 2, 5, RS2>(act, Wbf + 149504, 256, bb3, wave * 32, l15, quad);

    for (int e = tid; e < 8 * 32; e += 512) {
        int li = e >> 5, s = e & 31;
        int r0 = li * 9;
        float mx[8];
#pragma unroll
        for (int i = 0; i < 8; ++i) mx[i] = -3.0e38f;
#pragma unroll
        for (int kk = 0; kk < 9; ++kk) {
            u16x8 v = *(const u16x8*)(act + (r0 + kk) * RS2 + s * 8);
#pragma unroll
            for (int i = 0; i < 8; ++i) mx[i] = fmaxf(mx[i], bf2f(v[i]));
        }
        u16x8 o;
#pragma unroll
        for (int i = 0; i < 8; ++i) o[i] = f2bf(mx[i]);
#pragma unroll
        for (int kk = 0; kk < 9; ++kk)
            *(u16x8*)(act + (r0 + kk) * RS2 + 256 + s * 8) = o;
    }
    __syncthreads();

    conv_inplace<16, 4, 5, RS2>(act, Wbf + 215040, 512, ba1, wave * 64, l15, quad);
    conv_inplace<16, 4, 5, RS2>(act, Wbf + 477184, 512, ba2, wave * 64, l15, quad);

    for (int e = tid; e < 8 * 64; e += 512) {
        int li = e >> 6, s = e & 63;
        int r0 = li * 9;
        float mx[8];
#pragma unroll
        for (int i = 0; i < 8; ++i) mx[i] = -3.0e38f;
#pragma unroll
        for (int kk = 0; kk < 9; ++kk) {
            u16x8 v = *(const u16x8*)(act + (r0 + kk) * RS2 + s * 8);
#pragma unroll
            for (int i = 0; i < 8; ++i) mx[i] = fmaxf(mx[i], bf2f(v[i]));
        }
        u16x8 o;
#pragma unroll
        for (int i = 0; i < 8; ++i) o[i] = f2bf(mx[i]);
        *(u16x8*)(h + (size_t)(node0 + li) * 640 + 128 + s * 8) = o;
    }
}

// ---------------------------------------------------------------------------
// Fused stage 3: 256 blocks x 8 nodes, 512 threads.
// ---------------------------------------------------------------------------
static constexpr int RS3 = 648;

__global__ __launch_bounds__(512, 2) void fused_stage3_kernel(
    const float* __restrict__ node, const u16* __restrict__ h,
    const u16* __restrict__ Wbf,
    const float* __restrict__ bm1, const float* __restrict__ bm2,
    const float* __restrict__ w3, const float* __restrict__ b3,
    float* __restrict__ out) {
    __shared__ __align__(16) u16 act[16 * RS3];   // 20,736 B
    int blk = blockIdx.x;              // 0..255
    int node0 = blk * 8;
    int tid = threadIdx.x, lane = tid & 63, wave = tid >> 6;
    int quad = lane >> 4, l15 = lane & 15;

    for (int e = tid; e < 16 * 80; e += 512) {
        int r = e / 80, seg = e - r * 80;
        u16x8 v = (r < 8) ? *(const u16x8*)(h + (size_t)(node0 + r) * 640 + seg * 8)
                          : (u16x8){0,0,0,0,0,0,0,0};
        *(u16x8*)(act + r * RS3 + seg * 8) = v;
    }
    __syncthreads();

    conv_inplace<20, 4, 1, RS3>(act, Wbf + 739328, 640, bm1, wave * 64, l15, quad);
    conv_inplace<16, 2, 1, RS3>(act, Wbf + 1067008, 512, bm2, wave * 32, l15, quad);

    if (tid < 32) {
        int li = tid >> 2, oc = tid & 3;
        const u16* row = act + li * RS3;
        const float* wrow = w3 + oc * 256;
        float a = 0.0f;
        for (int c = 0; c < 256; c += 4) {
            a += bf2f(row[c]) * wrow[c];
            a += bf2f(row[c + 1]) * wrow[c + 1];
            a += bf2f(row[c + 2]) * wrow[c + 2];
            a += bf2f(row[c + 3]) * wrow[c + 3];
        }
        a += b3[oc];
        int nodei = node0 + li;
        int b = nodei >> 9, m = nodei & 511;
        if (oc < 3) {
            float nv = node[((size_t)b * 3 + oc) * M_ + m];
            out[((size_t)b * 3 + oc) * M_ + m] = nv;
            out[6144 + ((size_t)b * 3 + oc) * M_ + m] = nv + a;
        } else {
            out[12288 + nodei] = fmaxf(a, 0.0f) + log1pf(expf(-fabsf(a))) + 0.001f;
        }
    }
}

// ---------------------------------------------------------------------------
extern "C" void kernel_launch(void* const* d_in, const int* in_sizes, int n_in,
                              void* d_out, int out_size, void* d_ws, size_t ws_size,
                              hipStream_t stream) {
    (void)in_sizes; (void)n_in; (void)out_size; (void)ws_size;
    const float* x = (const float*)d_in[0];
    const float* sn = (const float*)d_in[1];
    const float* node = (const float*)d_in[2];
    const float* W[13];
    const float* Bs[13];
    for (int i = 0; i < 13; ++i) {
        W[i] = (const float*)d_in[3 + 2 * i];
        Bs[i] = (const float*)d_in[4 + 2 * i];
    }
    float* out = (float*)d_out;

    char* ws = (char*)d_ws;
    int* idx = (int*)(ws + 0);                 //   524,288
    int* knn = (int*)(ws + 524288);            //    73,728
    u16* Wbf = (u16*)(ws + 598016);            // 2,396,160
    u16* h   = (u16*)(ws + 2994176);           // 2,621,440 (2048 x 640)

    WConvArgs wa;
    for (int w = 0; w < 12; ++w) wa.src[w] = W[w];

    prep_kernel<<<7240, 256, 0, stream>>>(x, node, idx, knn, wa, Wbf);

    fused_stage1_kernel<<<512, 256, 0, stream>>>(x, sn, node, idx, Wbf,
                                                 Bs[0], Bs[1], Bs[2], Bs[3], Bs[4], h);
    fused_stage2_kernel<<<256, 512, 0, stream>>>(node, h, knn, Wbf,
                                                 Bs[5], Bs[6], Bs[7], Bs[8], Bs[9]);
    fused_stage3_kernel<<<256, 512, 0, stream>>>(node, h, Wbf, Bs[10], Bs[11],
                                                 W[12], Bs[12], out);
}